// Round 20
// baseline (68.479 us; speedup 1.0000x reference)
//
#include <hip/hip_runtime.h>

typedef __bf16 bf16x8 __attribute__((ext_vector_type(8)));
typedef float f32x4 __attribute__((ext_vector_type(4)));
typedef float f32x16 __attribute__((ext_vector_type(16)));

#define DEV static __device__ __forceinline__

DEV unsigned short f2bf(float f) {
    union { __bf16 h; unsigned short s; } c; c.h = (__bf16)f; return c.s;
}
DEV float bf2f(unsigned short h) {
    union { unsigned u; float f; } c; c.u = ((unsigned)h) << 16; return c.f;
}
DEV unsigned packbf2(float a, float b) {
    union { __bf16 h[2]; unsigned u; } c;
    c.h[0] = (__bf16)a; c.h[1] = (__bf16)b; return c.u;
}

DEV f32x4 mfma16(bf16x8 a, bf16x8 b, f32x4 c) {
    return __builtin_amdgcn_mfma_f32_16x16x32_bf16(a, b, c, 0, 0, 0);
}
DEV f32x16 mfma32(bf16x8 a, bf16x8 b, f32x16 c) {
    return __builtin_amdgcn_mfma_f32_32x32x16_bf16(a, b, c, 0, 0, 0);
}

#define GLOAD16(gp, lp)                                                        \
    __builtin_amdgcn_global_load_lds(                                          \
        (const __attribute__((address_space(1))) unsigned int*)(gp),           \
        (__attribute__((address_space(3))) unsigned int*)(lp), 16, 0, 0)

// barrier + scheduling pin: raw s_barrier is NOT a compiler fence (rule #18);
// sched_barrier(0) prevents hipcc from hoisting LDS reads above the barrier.
#define BARRIER_PINNED()                                                       \
    __builtin_amdgcn_s_barrier();                                              \
    __builtin_amdgcn_sched_barrier(0)

// --------------------- LN -> y bf16 (blocks < 2048) + weight transpose tiles
__global__ __launch_bounds__(256) void ln_conv_kernel(const float* __restrict__ x,
                                                      const float* __restrict__ lnsc,
                                                      unsigned short* __restrict__ y,
                                                      float* __restrict__ ssq,
                                                      const float* __restrict__ wqkv,
                                                      const float* __restrict__ wout,
                                                      unsigned short* __restrict__ wqkvt,
                                                      unsigned short* __restrict__ woutt) {
    const int t = threadIdx.x;
    if (blockIdx.x >= 2048) {
        // 64x64 LDS tile transpose, fp32 -> bf16, coalesced both sides.
        __shared__ __bf16 tile[64][65];
        const int wblk = blockIdx.x - 2048;
        const float* src;
        unsigned short* dst;
        int ldsrc, k0, f0;
        if (wblk < 192) {  // w_qkv [512,1536] -> wqkvt [1536,512]
            src = wqkv; dst = wqkvt; ldsrc = 1536;
            k0 = (wblk / 24) * 64; f0 = (wblk % 24) * 64;
        } else {           // w_out [512,512] -> woutt [512,512]
            int w2 = wblk - 192;
            src = wout; dst = woutt; ldsrc = 512;
            k0 = (w2 >> 3) * 64; f0 = (w2 & 7) * 64;
        }
#pragma unroll
        for (int j = 0; j < 16; j++) {
            int idx = t + j * 256;
            int a = idx >> 6, b2 = idx & 63;
            tile[b2][a] = (__bf16)src[(size_t)(k0 + a) * ldsrc + f0 + b2];
        }
        __syncthreads();
#pragma unroll
        for (int j = 0; j < 16; j++) {
            int idx = t + j * 256;
            int fb = idx >> 6, kc = idx & 63;
            union { __bf16 h; unsigned short s; } cv;
            cv.h = tile[fb][kc];
            dst[(size_t)(f0 + fb) * 512 + k0 + kc] = cv.s;
        }
        return;
    }
    if (blockIdx.x < 32) ssq[(blockIdx.x << 8) | t] = 0.0f;  // zero norm accumulators
    const int token = blockIdx.x * 4 + (t >> 6);
    const int lane = t & 63;
    const float4* xp = (const float4*)(x + (size_t)token * 512 + lane * 8);
    float4 v0 = xp[0], v1 = xp[1];
    float s = v0.x + v0.y + v0.z + v0.w + v1.x + v1.y + v1.z + v1.w;
    float s2 = v0.x * v0.x + v0.y * v0.y + v0.z * v0.z + v0.w * v0.w +
               v1.x * v1.x + v1.y * v1.y + v1.z * v1.z + v1.w * v1.w;
#pragma unroll
    for (int off = 1; off < 64; off <<= 1) {
        s += __shfl_xor(s, off);
        s2 += __shfl_xor(s2, off);
    }
    const float mean = s * (1.0f / 512.0f);
    const float var = s2 * (1.0f / 512.0f) - mean * mean;
    const float rstd = rsqrtf(var + 1e-5f);
    const float4* sp = (const float4*)(lnsc + lane * 8);
    float4 sc0 = sp[0], sc1 = sp[1];
    union { __bf16 h[8]; uint4 v; } pk;
    pk.h[0] = (__bf16)((v0.x - mean) * rstd * sc0.x);
    pk.h[1] = (__bf16)((v0.y - mean) * rstd * sc0.y);
    pk.h[2] = (__bf16)((v0.z - mean) * rstd * sc0.z);
    pk.h[3] = (__bf16)((v0.w - mean) * rstd * sc0.w);
    pk.h[4] = (__bf16)((v1.x - mean) * rstd * sc1.x);
    pk.h[5] = (__bf16)((v1.y - mean) * rstd * sc1.y);
    pk.h[6] = (__bf16)((v1.z - mean) * rstd * sc1.z);
    pk.h[7] = (__bf16)((v1.w - mean) * rstd * sc1.w);
    *(uint4*)(y + (size_t)token * 512 + lane * 8) = pk.v;
}

// ------------------------------------------------------- GEMM C = A * Bt^T
// A: [M,K] bf16 row-major, Bt: [N,K] bf16 row-major. Block tile 2WM x 2WN,
// templated BK, 4 waves (2x2). XOR-swizzled LDS via pre-swizzled global
// source (BK=64: (row&7)<<4 over 128B rows; BK=32: ((row>>1)&3)<<4 over 64B
// rows — both verified 2 lanes/bank = conflict-free). T1: row-tile on x.
// RING: 3-buffer ring, ONE pinned barrier per K-step, counted vmcnt(4):
//   B(t): vmcnt drains stage(t), leaves stage(t+1) in flight across the
//   barrier; stage(t+2) issued after the barrier targets ring[(t-1)%3],
//   whose compute the barrier just certified complete (WAR-safe).
//   Same occupancy (48KB LDS -> 3 blocks/CU) and barrier count as the
//   2-phase baseline — isolates the counted-vmcnt effect (T4).
// DB: classic double-buffer (used by gemm_out).
// QKV mode: Q (bC<4) -> qbuf row-major; K (bC 4..7) -> kst; V (bC>=8) -> vst.
template <int WM, int WN, int BK, int NCOLS, bool OUT_BF16, bool BIAS, bool QKV,
          bool DB, bool RING>
__global__ __launch_bounds__(256) void gemm_bt(const unsigned short* __restrict__ A,
                                               const unsigned short* __restrict__ Bt,
                                               void* __restrict__ Cout,
                                               const float* __restrict__ bias,
                                               float* __restrict__ ssq,
                                               unsigned short* __restrict__ kst,
                                               unsigned short* __restrict__ vst,
                                               int M, int K) {
    constexpr int BM = 2 * WM, BN = 2 * WN;
    constexpr int RB = BK * 2;  // row bytes
    constexpr int ASZ = BM * RB, BSZ = BN * RB;
    constexpr int NLA = ASZ / 4096, NLB = BSZ / 4096;  // gloads/thread/stage
    constexpr int MI = WM / 16, NI = WN / 16;          // acc dims
    constexpr int NBUF = RING ? 3 : (DB ? 2 : 1);
    constexpr int STG = NBUF * (ASZ + BSZ);
    constexpr int TTB = QKV ? 128 * 136 * 2 : 0;
    constexpr int LDSB = STG > TTB ? STG : TTB;
    __shared__ __align__(16) char smem[LDSB];
    const int t = threadIdx.x;
    const int w = t >> 6, lane = t & 63;
    const int g = lane >> 4, l15 = lane & 15;
    const int wr = w >> 1, wc = w & 1;
    const int bR = blockIdx.x, bC = blockIdx.y;  // row-tile on x (XCD locality)
    f32x4 acc[MI][NI] = {};
    const size_t ldb = (size_t)K * 2;
    const char* Ag = (const char*)A + (size_t)bR * BM * ldb;
    const char* Bg = (const char*)Bt + (size_t)bC * BN * ldb;

#define SWZ(row) (BK == 64 ? (((row)&7) << 4) : ((((row) >> 1) & 3) << 4))

#define GSTAGE(buf, kt_)                                                            \
    {                                                                               \
        char* Ad = smem + (buf) * (ASZ + BSZ);                                      \
        char* Bd = Ad + ASZ;                                                        \
        _Pragma("unroll") for (int i = 0; i < NLA; i++) {                           \
            int o = i * 4096 + t * 16;                                              \
            int row = o / RB, kb = (o % RB) ^ SWZ(row);                             \
            GLOAD16(Ag + (size_t)row * ldb + (size_t)(kt_) * 2 + kb, Ad + o);       \
        }                                                                           \
        _Pragma("unroll") for (int i = 0; i < NLB; i++) {                           \
            int o = i * 4096 + t * 16;                                              \
            int row = o / RB, kb = (o % RB) ^ SWZ(row);                             \
            GLOAD16(Bg + (size_t)row * ldb + (size_t)(kt_) * 2 + kb, Bd + o);       \
        }                                                                           \
    }

#define GCOMPUTE(buf)                                                               \
    {                                                                               \
        const char* Ab = smem + (buf) * (ASZ + BSZ);                                \
        const char* Bb = Ab + ASZ;                                                  \
        _Pragma("unroll") for (int kk = 0; kk < BK; kk += 32) {                     \
            bf16x8 a[MI], bb[NI];                                                   \
            _Pragma("unroll") for (int m = 0; m < MI; m++) {                        \
                int row = wr * WM + m * 16 + l15;                                   \
                int kb = ((kk + g * 8) * 2) ^ SWZ(row);                             \
                a[m] = *(const bf16x8*)(Ab + row * RB + kb);                        \
            }                                                                       \
            _Pragma("unroll") for (int n = 0; n < NI; n++) {                        \
                int row = wc * WN + n * 16 + l15;                                   \
                int kb = ((kk + g * 8) * 2) ^ SWZ(row);                             \
                bb[n] = *(const bf16x8*)(Bb + row * RB + kb);                       \
            }                                                                       \
            _Pragma("unroll") for (int m = 0; m < MI; m++)                          \
                _Pragma("unroll") for (int n = 0; n < NI; n++)                      \
                    acc[m][n] = mfma16(a[m], bb[n], acc[m][n]);                     \
        }                                                                           \
    }

    const int NT = K / BK;
    if constexpr (RING) {
        GSTAGE(0, 0)
        GSTAGE(1, BK)
        int slot = 0;  // ring slot of tile tt (tt % 3)
        for (int tt = 0; tt < NT; ++tt) {
            if (tt + 1 < NT) {
                asm volatile("s_waitcnt vmcnt(%0)" ::"n"(NLA + NLB) : "memory");
            } else {
                asm volatile("s_waitcnt vmcnt(0)" ::: "memory");
            }
            BARRIER_PINNED();
            if (tt + 2 < NT) {
                const int s2 = slot == 0 ? 2 : slot - 1;  // (tt+2) % 3
                GSTAGE(s2, (tt + 2) * BK)
            }
            GCOMPUTE(slot)
            slot = slot == 2 ? 0 : slot + 1;
        }
    } else if constexpr (DB) {
        GSTAGE(0, 0)
        for (int tt = 0; tt < NT; ++tt) {
            const int cur = tt & 1;
            if (tt + 1 < NT) {
                GSTAGE(cur ^ 1, (tt + 1) * BK)
                asm volatile("s_waitcnt vmcnt(%0)" ::"n"(NLA + NLB) : "memory");
            } else {
                asm volatile("s_waitcnt vmcnt(0)" ::: "memory");
            }
            BARRIER_PINNED();
            GCOMPUTE(cur)
            BARRIER_PINNED();
        }
    } else {
        for (int tt = 0; tt < NT; ++tt) {
            __syncthreads();
            GSTAGE(0, tt * BK)
            asm volatile("s_waitcnt vmcnt(0)" ::: "memory");
            __syncthreads();
            GCOMPUTE(0)
        }
    }
#undef GSTAGE
#undef GCOMPUTE
#undef SWZ

    const int rbase = bR * BM + wr * WM;
    const int cbase = bC * BN + wc * WN;
    if (!QKV || bC < 4) {
#pragma unroll
        for (int m = 0; m < MI; m++)
#pragma unroll
            for (int n = 0; n < NI; n++)
#pragma unroll
                for (int r = 0; r < 4; r++) {
                    int row = rbase + m * 16 + g * 4 + r;
                    int col = cbase + n * 16 + l15;
                    float v = acc[m][n][r];
                    if constexpr (OUT_BF16)
                        ((unsigned short*)Cout)[(size_t)row * NCOLS + col] = f2bf(v);
                    else
                        ((float*)Cout)[(size_t)row * NCOLS + col] =
                            v + (BIAS ? bias[col] : 0.f);
                }
    }
    if constexpr (QKV) {
        if (bC < 8) {  // q,k columns: sum-of-squares for l2norm folding
            const int bb2 = bR >> 3;
#pragma unroll
            for (int n = 0; n < NI; n++) {
                float ps = 0.f;
#pragma unroll
                for (int m = 0; m < MI; m++)
#pragma unroll
                    for (int r = 0; r < 4; r++) ps += acc[m][n][r] * acc[m][n][r];
                ps += __shfl_xor(ps, 16);
                ps += __shfl_xor(ps, 32);
                if (g == 0)
                    atomicAdd(&ssq[bb2 * 1024 + cbase + n * 16 + l15], ps);
            }
        }
        if (bC >= 4) {  // K or V: chunk-transposed outputs via LDS tile
            unsigned short* TT = (unsigned short*)smem;
            const bool isK = bC < 8;
            __syncthreads();  // all K-loop LDS reads done before overwrite
#pragma unroll
            for (int m = 0; m < MI; m++)
#pragma unroll
                for (int n = 0; n < NI; n++)
#pragma unroll
                    for (int r = 0; r < 4; r++) {
                        int row = wr * WM + m * 16 + g * 4 + r;  // token-local
                        int col = wc * WN + n * 16 + l15;        // f-local
                        if (isK)
                            TT[row * 136 + col] = f2bf(acc[m][n][r]);
                        else
                            TT[col * 136 + row] = f2bf(acc[m][n][r]);
                    }
            __syncthreads();
            const int b2 = bR >> 3, rb = bR & 7;
            if (isK) {
                // kst[bh][slot s(0..7)][n]: chunk = K[n][s*8..+8) (within head)
#pragma unroll
                for (int j = 0; j < 8; j++) {
                    int sl = (t >> 7) + j * 2;  // 0..15 (2 heads x 8 slots)
                    int nl = t & 127;
                    int hh = (bC - 4) * 2 + (sl >> 3), s = sl & 7;
                    *(uint4*)(kst +
                              (((size_t)(b2 * 8 + hh) * 8 + s) * 1024 + rb * 128 + nl) *
                                  8) = *(const uint4*)(TT + nl * 136 + sl * 8);
                }
            } else {
                // vst[bh][kvslot sv(0..127)][d]: chunk = V[sv*8..+8)[d]
#pragma unroll
                for (int j = 0; j < 8; j++) {
                    int fl = t & 127;
                    int svl = (t >> 7) + j * 2;  // 0..15
                    int hh = (bC - 8) * 2 + (fl >> 6), d = fl & 63;
                    *(uint4*)(vst +
                              (((size_t)(b2 * 8 + hh) * 128 + rb * 16 + svl) * 64 + d) *
                                  8) = *(const uint4*)(TT + fl * 136 + svl * 8);
                }
            }
        }
    }
}

// ------------------------------------------------------- flash-ish attention
// grid: x = bh (64) [T1: XCD-pinned K/V], y = q-tile of 128. 512 threads =
// 8 waves: in-block kv-split (waves 0-3 kv[0:512], waves 4-7 kv[512:1024]).
// 4 waves/SIMD TLP. 32x32x16 MFMA, swapped QK^T, in-register P via cvt_pk +
// permlane32_swap. K/V from chunk-transposed kst/vst, dbuf LDS, vmcnt(4),
// BARRIER_PINNED (rule #18). Epilogue: LDS combine of the two kv-halves.
__global__ __launch_bounds__(512, 4) void attn_kernel(
    const unsigned short* __restrict__ qbuf, const unsigned short* __restrict__ kst,
    const unsigned short* __restrict__ vst, unsigned short* __restrict__ attnout,
    const float* __restrict__ ssq) {
    __shared__ __align__(16) char smem[66048];
    // K half-tile (buf,hf): smem + (buf*2+hf)*8192 ; V: +32768. smq at +65536.
    float* smq = (float*)(smem + 65536);
    const int t = threadIdx.x, w = t >> 6, lane = t & 63;
    const int hi = lane >> 5, q31 = lane & 31;
    const int g2 = w >> 2, wq = w & 3;  // kv-half, q sub-tile
    const int qt = blockIdx.y, bh = blockIdx.x;  // bh on x: XCD locality
    const int b = bh >> 3, h = bh & 7;
    const size_t qrow0 = (size_t)b * 1024 + qt * 128;
    const char* kstb = (const char*)kst + (size_t)bh * 131072;
    const char* vstb = (const char*)vst + (size_t)bh * 131072;

    if (t < 64) {
        float nq = fmaxf(sqrtf(ssq[b * 1024 + h * 64 + t]), 1e-12f);
        float nk = fmaxf(sqrtf(ssq[b * 1024 + 512 + h * 64 + t]), 1e-12f);
        smq[t] = 14.42695040888963f / (nq * nk);  // 10*log2(e) folded in
    }
    __syncthreads();

    // Q B-fragments in registers, scaled. qf[ds]: Q[wq*32+q31][ds*16+hi*8+j]
    bf16x8 qf[4];
#pragma unroll
    for (int ds = 0; ds < 4; ds++) {
        union { bf16x8 v; unsigned short u[8]; } in, ov;
        in.v = *(const bf16x8*)(qbuf + (qrow0 + wq * 32 + q31) * 512 + h * 64 +
                                ds * 16 + hi * 8);
#pragma unroll
        for (int j = 0; j < 8; j++)
            ov.u[j] = f2bf(bf2f(in.u[j]) * smq[ds * 16 + hi * 8 + j]);
        qf[ds] = ov.v;
    }

    f32x16 accO[2] = {};
    float prs = 0.f;

    // stage tile tt_ for BOTH kv-halves: 512 threads x 4 gloads (2K + 2V).
#define ASTAGE(buf, tt_)                                                            \
    {                                                                               \
        _Pragma("unroll") for (int i = 0; i < 2; i++) {                             \
            const int c = i * 512 + t;                                              \
            const int hk = c >> 9, sl = (c >> 6) & 7, tl = c & 63;                  \
            GLOAD16(kstb + ((size_t)(sl * 1024 + hk * 512 + (tt_) * 64 + tl) << 4), \
                    smem + (((buf)*2 + hk) << 13) + sl * 1024 + tl * 16);           \
            GLOAD16(vstb + ((size_t)((hk * 64 + (tt_)*8 + sl) * 64 + tl) << 4),     \
                    smem + 32768 + (((buf)*2 + hk) << 13) + sl * 1024 + tl * 16);   \
        }                                                                           \
    }

    ASTAGE(0, 0)
    for (int tt = 0; tt < 8; ++tt) {
        const int cur = tt & 1;
        if (tt < 7) {
            ASTAGE(cur ^ 1, tt + 1)
            asm volatile("s_waitcnt vmcnt(4)" ::: "memory");
        } else {
            asm volatile("s_waitcnt vmcnt(0)" ::: "memory");
        }
        BARRIER_PINNED();
        const char* KsH = smem + ((cur * 2 + g2) << 13);
        const char* VsH = smem + 32768 + ((cur * 2 + g2) << 13);

#pragma unroll
        for (int kvb = 0; kvb < 2; kvb++) {
            // S^T = K Q^T : lane holds S[q=q31][kv row (r&3)+8*(r>>2)+4*hi]
            f32x16 sa = {};
            __builtin_amdgcn_s_setprio(1);
#pragma unroll
            for (int ds = 0; ds < 4; ds++) {
                bf16x8 kf = *(const bf16x8*)(KsH + ((ds * 2 + hi) << 10) +
                                             ((kvb * 32 + q31) << 4));
                sa = mfma32(kf, qf[ds], sa);
            }
            __builtin_amdgcn_s_setprio(0);
            // P = 2^s, rowsum, pack + permlane32_swap -> PV A-frags in regs
            float p[16];
#pragma unroll
            for (int r = 0; r < 16; r++) {
                p[r] = __builtin_amdgcn_exp2f(sa[r]);
                prs += p[r];
            }
            bf16x8 pf[2];
#pragma unroll
            for (int s2 = 0; s2 < 2; s2++) {
                unsigned a0 = packbf2(p[s2 * 8 + 0], p[s2 * 8 + 1]);
                unsigned a1 = packbf2(p[s2 * 8 + 2], p[s2 * 8 + 3]);
                unsigned b0 = packbf2(p[s2 * 8 + 4], p[s2 * 8 + 5]);
                unsigned b1 = packbf2(p[s2 * 8 + 6], p[s2 * 8 + 7]);
                asm volatile("v_permlane32_swap_b32 %0, %1" : "+v"(a0), "+v"(b0));
                asm volatile("v_permlane32_swap_b32 %0, %1" : "+v"(a1), "+v"(b1));
                union { unsigned u[4]; bf16x8 v; } fr;
                fr.u[0] = a0; fr.u[1] = a1; fr.u[2] = b0; fr.u[3] = b1;
                pf[s2] = fr.v;
            }
            // O^T += Vt * P^T
            __builtin_amdgcn_s_setprio(1);
#pragma unroll
            for (int s2 = 0; s2 < 2; s2++)
#pragma unroll
                for (int dvb = 0; dvb < 2; dvb++) {
                    bf16x8 vf = *(const bf16x8*)(VsH + ((kvb * 4 + s2 * 2 + hi) << 10) +
                                                 ((dvb * 32 + q31) << 4));
                    accO[dvb] = mfma32(vf, pf[s2], accO[dvb]);
                }
            __builtin_amdgcn_s_setprio(0);
        }
        BARRIER_PINNED();
    }
#undef ASTAGE

    // ------- combine the two kv-halves via LDS (stride 36 f32, 16B aligned)
    __syncthreads();
    float* comb = (float*)smem;
    float* pe = comb + (wq * 64 + lane) * 36;
    if (g2 == 1) {
        union { f32x16 v; float4 q[4]; } u0, u1;
        u0.v = accO[0]; u1.v = accO[1];
        *(float4*)(pe + 0) = u0.q[0];
        *(float4*)(pe + 4) = u0.q[1];
        *(float4*)(pe + 8) = u0.q[2];
        *(float4*)(pe + 12) = u0.q[3];
        *(float4*)(pe + 16) = u1.q[0];
        *(float4*)(pe + 20) = u1.q[1];
        *(float4*)(pe + 24) = u1.q[2];
        *(float4*)(pe + 28) = u1.q[3];
        pe[32] = prs;
    }
    __syncthreads();
    if (g2 == 0) {
        union { f32x16 v; float4 q[4]; } u0, u1;
        u0.q[0] = *(const float4*)(pe + 0);
        u0.q[1] = *(const float4*)(pe + 4);
        u0.q[2] = *(const float4*)(pe + 8);
        u0.q[3] = *(const float4*)(pe + 12);
        u1.q[0] = *(const float4*)(pe + 16);
        u1.q[1] = *(const float4*)(pe + 20);
        u1.q[2] = *(const float4*)(pe + 24);
        u1.q[3] = *(const float4*)(pe + 28);
        accO[0] += u0.v;
        accO[1] += u1.v;
        prs += pe[32];
        // full rowsum = own + partner(lane^32); divide; store b64 runs
        const float tot = prs + __shfl_xor(prs, 32);
        const float inv = 1.0f / tot;
        unsigned short* orow = attnout + (qrow0 + wq * 32 + q31) * 512 + h * 64;
#pragma unroll
        for (int dvb = 0; dvb < 2; dvb++)
#pragma unroll
            for (int grp = 0; grp < 4; grp++) {
                float f0 = accO[dvb][grp * 4 + 0] * inv;
                float f1 = accO[dvb][grp * 4 + 1] * inv;
                float f2 = accO[dvb][grp * 4 + 2] * inv;
                float f3 = accO[dvb][grp * 4 + 3] * inv;
                uint2 pk;
                pk.x = packbf2(f0, f1);
                pk.y = packbf2(f2, f3);
                *(uint2*)(orow + dvb * 32 + grp * 8 + 4 * hi) = pk;
            }
    }
}

// ---------------------------------------------------------------- launcher
extern "C" void kernel_launch(void* const* d_in, const int* in_sizes, int n_in,
                              void* d_out, int out_size, void* d_ws, size_t ws_size,
                              hipStream_t stream) {
    const float* x = (const float*)d_in[0];
    const float* ln_scale = (const float*)d_in[1];
    const float* w_qkv = (const float*)d_in[2];
    const float* w_out = (const float*)d_in[3];
    const float* b_out = (const float*)d_in[4];
    float* out = (float*)d_out;

    char* ws = (char*)d_ws;
    unsigned short* y = (unsigned short*)(ws + 0);            // 8 MB (reused: attnout)
    unsigned short* wqkvt = (unsigned short*)(ws + 8388608);  // 1.5 MB
    unsigned short* woutt = (unsigned short*)(ws + 9961472);  // 0.5 MB
    unsigned short* qbuf = (unsigned short*)(ws + 10485760);  // 8 MB [8192x512]
    unsigned short* kst = (unsigned short*)(ws + 18874368);   // 8 MB [bh][8][1024]x16B
    unsigned short* vst = (unsigned short*)(ws + 27262976);   // 8 MB [bh][128][64]x16B
    float* ssq = (float*)(ws + 35651584);                     // 32 KB
    unsigned short* attnout = (unsigned short*)(ws + 0);      // overlaps y (dead)

    ln_conv_kernel<<<2304, 256, 0, stream>>>(x, ln_scale, y, ssq, w_qkv, w_out, wqkvt,
                                             woutt);
    gemm_bt<64, 64, 32, 512, true, false, true, false, true>
        <<<dim3(64, 12), 256, 0, stream>>>(y, wqkvt, qbuf, nullptr, ssq, kst, vst,
                                           8192, 512);
    attn_kernel<<<dim3(64, 8), 512, 0, stream>>>(qbuf, kst, vst, attnout, ssq);
    gemm_bt<32, 64, 64, 512, false, true, false, true, false>
        <<<dim3(128, 4), 256, 0, stream>>>(attnout, woutt, out, b_out, nullptr, nullptr,
                                           nullptr, 8192, 512);
}

// Round 21
// 66.785 us; speedup vs baseline: 1.0254x; 1.0254x over previous
//
#include <hip/hip_runtime.h>

typedef __bf16 bf16x8 __attribute__((ext_vector_type(8)));
typedef float f32x4 __attribute__((ext_vector_type(4)));
typedef float f32x16 __attribute__((ext_vector_type(16)));

#define DEV static __device__ __forceinline__

DEV unsigned short f2bf(float f) {
    union { __bf16 h; unsigned short s; } c; c.h = (__bf16)f; return c.s;
}
DEV float bf2f(unsigned short h) {
    union { unsigned u; float f; } c; c.u = ((unsigned)h) << 16; return c.f;
}
DEV unsigned packbf2(float a, float b) {
    union { __bf16 h[2]; unsigned u; } c;
    c.h[0] = (__bf16)a; c.h[1] = (__bf16)b; return c.u;
}

DEV f32x4 mfma16(bf16x8 a, bf16x8 b, f32x4 c) {
    return __builtin_amdgcn_mfma_f32_16x16x32_bf16(a, b, c, 0, 0, 0);
}
DEV f32x16 mfma32(bf16x8 a, bf16x8 b, f32x16 c) {
    return __builtin_amdgcn_mfma_f32_32x32x16_bf16(a, b, c, 0, 0, 0);
}

#define GLOAD16(gp, lp)                                                        \
    __builtin_amdgcn_global_load_lds(                                          \
        (const __attribute__((address_space(1))) unsigned int*)(gp),           \
        (__attribute__((address_space(3))) unsigned int*)(lp), 16, 0, 0)

// barrier + scheduling pin: raw s_barrier is NOT a compiler fence (rule #18);
// sched_barrier(0) prevents hipcc from hoisting LDS reads above the barrier.
#define BARRIER_PINNED()                                                       \
    __builtin_amdgcn_s_barrier();                                              \
    __builtin_amdgcn_sched_barrier(0)

// --------------------- LN -> y bf16 (blocks < 2048) + weight transpose tiles
__global__ __launch_bounds__(256) void ln_conv_kernel(const float* __restrict__ x,
                                                      const float* __restrict__ lnsc,
                                                      unsigned short* __restrict__ y,
                                                      float* __restrict__ ssq,
                                                      const float* __restrict__ wqkv,
                                                      const float* __restrict__ wout,
                                                      unsigned short* __restrict__ wqkvt,
                                                      unsigned short* __restrict__ woutt) {
    const int t = threadIdx.x;
    if (blockIdx.x >= 2048) {
        // 64x64 LDS tile transpose, fp32 -> bf16, coalesced both sides.
        __shared__ __bf16 tile[64][65];
        const int wblk = blockIdx.x - 2048;
        const float* src;
        unsigned short* dst;
        int ldsrc, k0, f0;
        if (wblk < 192) {  // w_qkv [512,1536] -> wqkvt [1536,512]
            src = wqkv; dst = wqkvt; ldsrc = 1536;
            k0 = (wblk / 24) * 64; f0 = (wblk % 24) * 64;
        } else {           // w_out [512,512] -> woutt [512,512]
            int w2 = wblk - 192;
            src = wout; dst = woutt; ldsrc = 512;
            k0 = (w2 >> 3) * 64; f0 = (w2 & 7) * 64;
        }
#pragma unroll
        for (int j = 0; j < 16; j++) {
            int idx = t + j * 256;
            int a = idx >> 6, b2 = idx & 63;
            tile[b2][a] = (__bf16)src[(size_t)(k0 + a) * ldsrc + f0 + b2];
        }
        __syncthreads();
#pragma unroll
        for (int j = 0; j < 16; j++) {
            int idx = t + j * 256;
            int fb = idx >> 6, kc = idx & 63;
            union { __bf16 h; unsigned short s; } cv;
            cv.h = tile[fb][kc];
            dst[(size_t)(f0 + fb) * 512 + k0 + kc] = cv.s;
        }
        return;
    }
    if (blockIdx.x < 32) ssq[(blockIdx.x << 8) | t] = 0.0f;  // zero norm accumulators
    const int token = blockIdx.x * 4 + (t >> 6);
    const int lane = t & 63;
    const float4* xp = (const float4*)(x + (size_t)token * 512 + lane * 8);
    float4 v0 = xp[0], v1 = xp[1];
    float s = v0.x + v0.y + v0.z + v0.w + v1.x + v1.y + v1.z + v1.w;
    float s2 = v0.x * v0.x + v0.y * v0.y + v0.z * v0.z + v0.w * v0.w +
               v1.x * v1.x + v1.y * v1.y + v1.z * v1.z + v1.w * v1.w;
#pragma unroll
    for (int off = 1; off < 64; off <<= 1) {
        s += __shfl_xor(s, off);
        s2 += __shfl_xor(s2, off);
    }
    const float mean = s * (1.0f / 512.0f);
    const float var = s2 * (1.0f / 512.0f) - mean * mean;
    const float rstd = rsqrtf(var + 1e-5f);
    const float4* sp = (const float4*)(lnsc + lane * 8);
    float4 sc0 = sp[0], sc1 = sp[1];
    union { __bf16 h[8]; uint4 v; } pk;
    pk.h[0] = (__bf16)((v0.x - mean) * rstd * sc0.x);
    pk.h[1] = (__bf16)((v0.y - mean) * rstd * sc0.y);
    pk.h[2] = (__bf16)((v0.z - mean) * rstd * sc0.z);
    pk.h[3] = (__bf16)((v0.w - mean) * rstd * sc0.w);
    pk.h[4] = (__bf16)((v1.x - mean) * rstd * sc1.x);
    pk.h[5] = (__bf16)((v1.y - mean) * rstd * sc1.y);
    pk.h[6] = (__bf16)((v1.z - mean) * rstd * sc1.z);
    pk.h[7] = (__bf16)((v1.w - mean) * rstd * sc1.w);
    *(uint4*)(y + (size_t)token * 512 + lane * 8) = pk.v;
}

// ------------------------------------------------------- GEMM C = A * Bt^T
// A: [M,K] bf16 row-major, Bt: [N,K] bf16 row-major. Block tile 2WM x 2WN,
// templated BK, 4 waves (2x2). XOR-swizzled LDS via pre-swizzled global
// source. T1: row-tile on blockIdx.x (lid%8 = bR%8 -> A-panel XCD locality).
// DB: double-buffered LDS + counted vmcnt + BARRIER_PINNED (only when LDS
// doesn't cut co-residency below the grid's blocks/CU — gemm_out qualifies).
// QKV single-buffer: measured-best (dbuf r4/r18/ring r20 all regressed).
// QKV mode: Q (bC<4) -> qbuf row-major; K (bC 4..7) -> kst; V (bC>=8) -> vst.
template <int WM, int WN, int BK, int NCOLS, bool OUT_BF16, bool BIAS, bool QKV,
          bool DB>
__global__ __launch_bounds__(256) void gemm_bt(const unsigned short* __restrict__ A,
                                               const unsigned short* __restrict__ Bt,
                                               void* __restrict__ Cout,
                                               const float* __restrict__ bias,
                                               float* __restrict__ ssq,
                                               unsigned short* __restrict__ kst,
                                               unsigned short* __restrict__ vst,
                                               int M, int K) {
    constexpr int BM = 2 * WM, BN = 2 * WN;
    constexpr int RB = BK * 2;           // row bytes
    constexpr int RMASK = BK / 8 - 1;    // swizzle row mask
    constexpr int ASZ = BM * RB, BSZ = BN * RB;
    constexpr int NLA = ASZ / 4096, NLB = BSZ / 4096;  // gloads/thread/stage
    constexpr int MI = WM / 16, NI = WN / 16;          // acc dims
    constexpr int NBUF = DB ? 2 : 1;
    constexpr int STG = NBUF * (ASZ + BSZ);
    constexpr int TTB = QKV ? 128 * 136 * 2 : 0;
    constexpr int LDSB = STG > TTB ? STG : TTB;
    __shared__ __align__(16) char smem[LDSB];
    const int t = threadIdx.x;
    const int w = t >> 6, lane = t & 63;
    const int g = lane >> 4, l15 = lane & 15;
    const int wr = w >> 1, wc = w & 1;
    const int bR = blockIdx.x, bC = blockIdx.y;  // row-tile on x (XCD locality)
    f32x4 acc[MI][NI] = {};
    const size_t ldb = (size_t)K * 2;
    const char* Ag = (const char*)A + (size_t)bR * BM * ldb;
    const char* Bg = (const char*)Bt + (size_t)bC * BN * ldb;

#define GSTAGE(buf, kt_)                                                            \
    {                                                                               \
        char* Ad = smem + (buf) * (ASZ + BSZ);                                      \
        char* Bd = Ad + ASZ;                                                        \
        _Pragma("unroll") for (int i = 0; i < NLA; i++) {                           \
            int o = i * 4096 + t * 16;                                              \
            int row = o / RB, kb = (o % RB) ^ ((row & RMASK) << 4);                 \
            GLOAD16(Ag + (size_t)row * ldb + (size_t)(kt_) * 2 + kb, Ad + o);       \
        }                                                                           \
        _Pragma("unroll") for (int i = 0; i < NLB; i++) {                           \
            int o = i * 4096 + t * 16;                                              \
            int row = o / RB, kb = (o % RB) ^ ((row & RMASK) << 4);                 \
            GLOAD16(Bg + (size_t)row * ldb + (size_t)(kt_) * 2 + kb, Bd + o);       \
        }                                                                           \
    }

#define GCOMPUTE(buf)                                                               \
    {                                                                               \
        const char* Ab = smem + (buf) * (ASZ + BSZ);                                \
        const char* Bb = Ab + ASZ;                                                  \
        _Pragma("unroll") for (int kk = 0; kk < BK; kk += 32) {                     \
            bf16x8 a[MI], bb[NI];                                                   \
            _Pragma("unroll") for (int m = 0; m < MI; m++) {                        \
                int row = wr * WM + m * 16 + l15;                                   \
                int kb = ((kk + g * 8) * 2) ^ ((row & RMASK) << 4);                 \
                a[m] = *(const bf16x8*)(Ab + row * RB + kb);                        \
            }                                                                       \
            _Pragma("unroll") for (int n = 0; n < NI; n++) {                        \
                int row = wc * WN + n * 16 + l15;                                   \
                int kb = ((kk + g * 8) * 2) ^ ((row & RMASK) << 4);                 \
                bb[n] = *(const bf16x8*)(Bb + row * RB + kb);                       \
            }                                                                       \
            _Pragma("unroll") for (int m = 0; m < MI; m++)                          \
                _Pragma("unroll") for (int n = 0; n < NI; n++)                      \
                    acc[m][n] = mfma16(a[m], bb[n], acc[m][n]);                     \
        }                                                                           \
    }

    const int NT = K / BK;
    if constexpr (DB) {
        GSTAGE(0, 0)
        for (int tt = 0; tt < NT; ++tt) {
            const int cur = tt & 1;
            if (tt + 1 < NT) {
                GSTAGE(cur ^ 1, (tt + 1) * BK)
                asm volatile("s_waitcnt vmcnt(%0)" ::"n"(NLA + NLB) : "memory");
            } else {
                asm volatile("s_waitcnt vmcnt(0)" ::: "memory");
            }
            BARRIER_PINNED();
            GCOMPUTE(cur)
            BARRIER_PINNED();
        }
    } else {
        for (int tt = 0; tt < NT; ++tt) {
            __syncthreads();
            GSTAGE(0, tt * BK)
            asm volatile("s_waitcnt vmcnt(0)" ::: "memory");
            __syncthreads();
            GCOMPUTE(0)
        }
    }
#undef GSTAGE
#undef GCOMPUTE

    const int rbase = bR * BM + wr * WM;
    const int cbase = bC * BN + wc * WN;
    if (!QKV || bC < 4) {
#pragma unroll
        for (int m = 0; m < MI; m++)
#pragma unroll
            for (int n = 0; n < NI; n++)
#pragma unroll
                for (int r = 0; r < 4; r++) {
                    int row = rbase + m * 16 + g * 4 + r;
                    int col = cbase + n * 16 + l15;
                    float v = acc[m][n][r];
                    if constexpr (OUT_BF16)
                        ((unsigned short*)Cout)[(size_t)row * NCOLS + col] = f2bf(v);
                    else
                        ((float*)Cout)[(size_t)row * NCOLS + col] =
                            v + (BIAS ? bias[col] : 0.f);
                }
    }
    if constexpr (QKV) {
        if (bC < 8) {  // q,k columns: sum-of-squares for l2norm folding
            const int bb2 = bR >> 3;
#pragma unroll
            for (int n = 0; n < NI; n++) {
                float ps = 0.f;
#pragma unroll
                for (int m = 0; m < MI; m++)
#pragma unroll
                    for (int r = 0; r < 4; r++) ps += acc[m][n][r] * acc[m][n][r];
                ps += __shfl_xor(ps, 16);
                ps += __shfl_xor(ps, 32);
                if (g == 0)
                    atomicAdd(&ssq[bb2 * 1024 + cbase + n * 16 + l15], ps);
            }
        }
        if (bC >= 4) {  // K or V: chunk-transposed outputs via LDS tile
            unsigned short* TT = (unsigned short*)smem;
            const bool isK = bC < 8;
            __syncthreads();  // all K-loop LDS reads done before overwrite
#pragma unroll
            for (int m = 0; m < MI; m++)
#pragma unroll
                for (int n = 0; n < NI; n++)
#pragma unroll
                    for (int r = 0; r < 4; r++) {
                        int row = wr * WM + m * 16 + g * 4 + r;  // token-local
                        int col = wc * WN + n * 16 + l15;        // f-local
                        if (isK)
                            TT[row * 136 + col] = f2bf(acc[m][n][r]);
                        else
                            TT[col * 136 + row] = f2bf(acc[m][n][r]);
                    }
            __syncthreads();
            const int b2 = bR >> 3, rb = bR & 7;
            if (isK) {
                // kst[bh][slot s(0..7)][n]: chunk = K[n][s*8..+8) (within head)
#pragma unroll
                for (int j = 0; j < 8; j++) {
                    int sl = (t >> 7) + j * 2;  // 0..15 (2 heads x 8 slots)
                    int nl = t & 127;
                    int hh = (bC - 4) * 2 + (sl >> 3), s = sl & 7;
                    *(uint4*)(kst +
                              (((size_t)(b2 * 8 + hh) * 8 + s) * 1024 + rb * 128 + nl) *
                                  8) = *(const uint4*)(TT + nl * 136 + sl * 8);
                }
            } else {
                // vst[bh][kvslot sv(0..127)][d]: chunk = V[sv*8..+8)[d]
#pragma unroll
                for (int j = 0; j < 8; j++) {
                    int fl = t & 127;
                    int svl = (t >> 7) + j * 2;  // 0..15
                    int hh = (bC - 8) * 2 + (fl >> 6), d = fl & 63;
                    *(uint4*)(vst +
                              (((size_t)(b2 * 8 + hh) * 128 + rb * 16 + svl) * 64 + d) *
                                  8) = *(const uint4*)(TT + fl * 136 + svl * 8);
                }
            }
        }
    }
}

// ------------------------------------------------------- flash-ish attention
// grid: x = bh (64) [T1: XCD-pinned K/V], y = q-tile of 128. 512 threads =
// 8 waves: in-block kv-split (waves 0-3 kv[0:512], waves 4-7 kv[512:1024]).
// 4 waves/SIMD TLP. 32x32x16 MFMA, swapped QK^T, in-register P via cvt_pk +
// permlane32_swap. K/V from chunk-transposed kst/vst, dbuf LDS, vmcnt(4),
// BARRIER_PINNED (rule #18). Epilogue: LDS combine of the two kv-halves.
__global__ __launch_bounds__(512, 4) void attn_kernel(
    const unsigned short* __restrict__ qbuf, const unsigned short* __restrict__ kst,
    const unsigned short* __restrict__ vst, unsigned short* __restrict__ attnout,
    const float* __restrict__ ssq) {
    __shared__ __align__(16) char smem[66048];
    // K half-tile (buf,hf): smem + (buf*2+hf)*8192 ; V: +32768. smq at +65536.
    float* smq = (float*)(smem + 65536);
    const int t = threadIdx.x, w = t >> 6, lane = t & 63;
    const int hi = lane >> 5, q31 = lane & 31;
    const int g2 = w >> 2, wq = w & 3;  // kv-half, q sub-tile
    const int qt = blockIdx.y, bh = blockIdx.x;  // bh on x: XCD locality
    const int b = bh >> 3, h = bh & 7;
    const size_t qrow0 = (size_t)b * 1024 + qt * 128;
    const char* kstb = (const char*)kst + (size_t)bh * 131072;
    const char* vstb = (const char*)vst + (size_t)bh * 131072;

    if (t < 64) {
        float nq = fmaxf(sqrtf(ssq[b * 1024 + h * 64 + t]), 1e-12f);
        float nk = fmaxf(sqrtf(ssq[b * 1024 + 512 + h * 64 + t]), 1e-12f);
        smq[t] = 14.42695040888963f / (nq * nk);  // 10*log2(e) folded in
    }
    __syncthreads();

    // Q B-fragments in registers, scaled. qf[ds]: Q[wq*32+q31][ds*16+hi*8+j]
    bf16x8 qf[4];
#pragma unroll
    for (int ds = 0; ds < 4; ds++) {
        union { bf16x8 v; unsigned short u[8]; } in, ov;
        in.v = *(const bf16x8*)(qbuf + (qrow0 + wq * 32 + q31) * 512 + h * 64 +
                                ds * 16 + hi * 8);
#pragma unroll
        for (int j = 0; j < 8; j++)
            ov.u[j] = f2bf(bf2f(in.u[j]) * smq[ds * 16 + hi * 8 + j]);
        qf[ds] = ov.v;
    }

    f32x16 accO[2] = {};
    float prs = 0.f;

    // stage tile tt_ for BOTH kv-halves: 512 threads x 4 gloads (2K + 2V).
#define ASTAGE(buf, tt_)                                                            \
    {                                                                               \
        _Pragma("unroll") for (int i = 0; i < 2; i++) {                             \
            const int c = i * 512 + t;                                              \
            const int hk = c >> 9, sl = (c >> 6) & 7, tl = c & 63;                  \
            GLOAD16(kstb + ((size_t)(sl * 1024 + hk * 512 + (tt_) * 64 + tl) << 4), \
                    smem + (((buf)*2 + hk) << 13) + sl * 1024 + tl * 16);           \
            GLOAD16(vstb + ((size_t)((hk * 64 + (tt_)*8 + sl) * 64 + tl) << 4),     \
                    smem + 32768 + (((buf)*2 + hk) << 13) + sl * 1024 + tl * 16);   \
        }                                                                           \
    }

    ASTAGE(0, 0)
    for (int tt = 0; tt < 8; ++tt) {
        const int cur = tt & 1;
        if (tt < 7) {
            ASTAGE(cur ^ 1, tt + 1)
            asm volatile("s_waitcnt vmcnt(4)" ::: "memory");
        } else {
            asm volatile("s_waitcnt vmcnt(0)" ::: "memory");
        }
        BARRIER_PINNED();
        const char* KsH = smem + ((cur * 2 + g2) << 13);
        const char* VsH = smem + 32768 + ((cur * 2 + g2) << 13);

#pragma unroll
        for (int kvb = 0; kvb < 2; kvb++) {
            // S^T = K Q^T : lane holds S[q=q31][kv row (r&3)+8*(r>>2)+4*hi]
            f32x16 sa = {};
            __builtin_amdgcn_s_setprio(1);
#pragma unroll
            for (int ds = 0; ds < 4; ds++) {
                bf16x8 kf = *(const bf16x8*)(KsH + ((ds * 2 + hi) << 10) +
                                             ((kvb * 32 + q31) << 4));
                sa = mfma32(kf, qf[ds], sa);
            }
            __builtin_amdgcn_s_setprio(0);
            // P = 2^s, rowsum, pack + permlane32_swap -> PV A-frags in regs
            float p[16];
#pragma unroll
            for (int r = 0; r < 16; r++) {
                p[r] = __builtin_amdgcn_exp2f(sa[r]);
                prs += p[r];
            }
            bf16x8 pf[2];
#pragma unroll
            for (int s2 = 0; s2 < 2; s2++) {
                unsigned a0 = packbf2(p[s2 * 8 + 0], p[s2 * 8 + 1]);
                unsigned a1 = packbf2(p[s2 * 8 + 2], p[s2 * 8 + 3]);
                unsigned b0 = packbf2(p[s2 * 8 + 4], p[s2 * 8 + 5]);
                unsigned b1 = packbf2(p[s2 * 8 + 6], p[s2 * 8 + 7]);
                asm volatile("v_permlane32_swap_b32 %0, %1" : "+v"(a0), "+v"(b0));
                asm volatile("v_permlane32_swap_b32 %0, %1" : "+v"(a1), "+v"(b1));
                union { unsigned u[4]; bf16x8 v; } fr;
                fr.u[0] = a0; fr.u[1] = a1; fr.u[2] = b0; fr.u[3] = b1;
                pf[s2] = fr.v;
            }
            // O^T += Vt * P^T
            __builtin_amdgcn_s_setprio(1);
#pragma unroll
            for (int s2 = 0; s2 < 2; s2++)
#pragma unroll
                for (int dvb = 0; dvb < 2; dvb++) {
                    bf16x8 vf = *(const bf16x8*)(VsH + ((kvb * 4 + s2 * 2 + hi) << 10) +
                                                 ((dvb * 32 + q31) << 4));
                    accO[dvb] = mfma32(vf, pf[s2], accO[dvb]);
                }
            __builtin_amdgcn_s_setprio(0);
        }
        BARRIER_PINNED();
    }
#undef ASTAGE

    // ------- combine the two kv-halves via LDS (stride 36 f32, 16B aligned)
    __syncthreads();
    float* comb = (float*)smem;
    float* pe = comb + (wq * 64 + lane) * 36;
    if (g2 == 1) {
        union { f32x16 v; float4 q[4]; } u0, u1;
        u0.v = accO[0]; u1.v = accO[1];
        *(float4*)(pe + 0) = u0.q[0];
        *(float4*)(pe + 4) = u0.q[1];
        *(float4*)(pe + 8) = u0.q[2];
        *(float4*)(pe + 12) = u0.q[3];
        *(float4*)(pe + 16) = u1.q[0];
        *(float4*)(pe + 20) = u1.q[1];
        *(float4*)(pe + 24) = u1.q[2];
        *(float4*)(pe + 28) = u1.q[3];
        pe[32] = prs;
    }
    __syncthreads();
    if (g2 == 0) {
        union { f32x16 v; float4 q[4]; } u0, u1;
        u0.q[0] = *(const float4*)(pe + 0);
        u0.q[1] = *(const float4*)(pe + 4);
        u0.q[2] = *(const float4*)(pe + 8);
        u0.q[3] = *(const float4*)(pe + 12);
        u1.q[0] = *(const float4*)(pe + 16);
        u1.q[1] = *(const float4*)(pe + 20);
        u1.q[2] = *(const float4*)(pe + 24);
        u1.q[3] = *(const float4*)(pe + 28);
        accO[0] += u0.v;
        accO[1] += u1.v;
        prs += pe[32];
        // full rowsum = own + partner(lane^32); divide; store b64 runs
        const float tot = prs + __shfl_xor(prs, 32);
        const float inv = 1.0f / tot;
        unsigned short* orow = attnout + (qrow0 + wq * 32 + q31) * 512 + h * 64;
#pragma unroll
        for (int dvb = 0; dvb < 2; dvb++)
#pragma unroll
            for (int grp = 0; grp < 4; grp++) {
                float f0 = accO[dvb][grp * 4 + 0] * inv;
                float f1 = accO[dvb][grp * 4 + 1] * inv;
                float f2 = accO[dvb][grp * 4 + 2] * inv;
                float f3 = accO[dvb][grp * 4 + 3] * inv;
                uint2 pk;
                pk.x = packbf2(f0, f1);
                pk.y = packbf2(f2, f3);
                *(uint2*)(orow + dvb * 32 + grp * 8 + 4 * hi) = pk;
            }
    }
}

// ---------------------------------------------------------------- launcher
extern "C" void kernel_launch(void* const* d_in, const int* in_sizes, int n_in,
                              void* d_out, int out_size, void* d_ws, size_t ws_size,
                              hipStream_t stream) {
    const float* x = (const float*)d_in[0];
    const float* ln_scale = (const float*)d_in[1];
    const float* w_qkv = (const float*)d_in[2];
    const float* w_out = (const float*)d_in[3];
    const float* b_out = (const float*)d_in[4];
    float* out = (float*)d_out;

    char* ws = (char*)d_ws;
    unsigned short* y = (unsigned short*)(ws + 0);            // 8 MB (reused: attnout)
    unsigned short* wqkvt = (unsigned short*)(ws + 8388608);  // 1.5 MB
    unsigned short* woutt = (unsigned short*)(ws + 9961472);  // 0.5 MB
    unsigned short* qbuf = (unsigned short*)(ws + 10485760);  // 8 MB [8192x512]
    unsigned short* kst = (unsigned short*)(ws + 18874368);   // 8 MB [bh][8][1024]x16B
    unsigned short* vst = (unsigned short*)(ws + 27262976);   // 8 MB [bh][128][64]x16B
    float* ssq = (float*)(ws + 35651584);                     // 32 KB
    unsigned short* attnout = (unsigned short*)(ws + 0);      // overlaps y (dead)

    ln_conv_kernel<<<2304, 256, 0, stream>>>(x, ln_scale, y, ssq, w_qkv, w_out, wqkvt,
                                             woutt);
    gemm_bt<64, 64, 64, 512, true, false, true, false>
        <<<dim3(64, 12), 256, 0, stream>>>(y, wqkvt, qbuf, nullptr, ssq, kst, vst,
                                           8192, 512);
    attn_kernel<<<dim3(64, 8), 512, 0, stream>>>(qbuf, kst, vst, attnout, ssq);
    gemm_bt<32, 64, 64, 512, false, true, false, true>
        <<<dim3(128, 4), 256, 0, stream>>>(attnout, woutt, out, b_out, nullptr, nullptr,
                                           nullptr, 8192, 512);
}